// Round 3
// baseline (522.116 us; speedup 1.0000x reference)
//
#include <hip/hip_runtime.h>
#include <cstdint>
#include <cstddef>

// Problem constants
#define Bn   32
#define Cn   256
#define Hn   56
#define Wn   56
#define HWn  (Hn*Wn)            // 3136
#define WELEMS (Cn*Cn*9)        // 589824
#define EPSv 1e-5f

// Padded int8 activation layout: [b][58][58][256] int8
#define PR   58
#define PPB  (PR*PR)            // 3364 padded pixels per batch
#define NPP  (Bn*PPB)           // 107648
#define MARG 64                 // guard pixels each side (tap offsets reach +/-59)

// ws layout (byte offsets)
#define F_WABS 0                // float
#define F_SUM  64               // float[256]
#define F_SQ   320              // float[256]
#define STATS_BYTES 4096
#define BPK_OFF 8192            // int8 Bpk[9][8][8][64][16] = 589824 B
#define XI8_OFF 598016          // int8 xi8[(NPP+2*MARG)*256] = 27590656 B
// total ws needed ~= 28.2 MB

typedef int v4i  __attribute__((ext_vector_type(4)));
typedef int v16i __attribute__((ext_vector_type(16)));

// ---------------------------------------------------------------------------
// Pack weights into MFMA B-fragment order + reduce sum(|clip(w,-1,1)|).
// Bpk index: (((tap*8 + cib)*8 + cob)*64 + lane)*16 + j
//   byte = sign(w[co][ci][tap]), co = cob*32 + (lane&31),
//   ci = cib*32 + (lane>>5)*16 + j   (B[k][n]: n=lane&31, k=16*(lane>>5)+j)
__global__ void pack_w_kernel(const float* __restrict__ w,
                              float* __restrict__ wsf,
                              int8_t* __restrict__ bpk) {
    int u = blockIdx.x * 256 + threadIdx.x;   // 144*256 = 36864 exactly
    int lane = u & 63;
    int cob  = (u >> 6) & 7;
    int cib  = (u >> 9) & 7;
    int tap  = u >> 12;                       // 0..8
    int co  = cob * 32 + (lane & 31);
    int ci0 = cib * 32 + (lane >> 5) * 16;

    float sabs = 0.0f;
    uint32_t wrd[4];
    #pragma unroll
    for (int q = 0; q < 4; q++) {
        uint32_t acc = 0;
        #pragma unroll
        for (int j = 0; j < 4; j++) {
            float wv = w[((size_t)co * 256 + ci0 + q * 4 + j) * 9 + tap];
            sabs += fminf(fabsf(wv), 1.0f);
            uint32_t byte = (wv < 0.0f) ? 0xFFu : 0x01u;
            acc |= byte << (8 * j);
        }
        wrd[q] = acc;
    }
    *(uint4*)(bpk + (size_t)u * 16) = make_uint4(wrd[0], wrd[1], wrd[2], wrd[3]);

    #pragma unroll
    for (int off = 32; off; off >>= 1) sabs += __shfl_down(sabs, off);
    __shared__ float sh[4];
    if ((threadIdx.x & 63) == 0) sh[threadIdx.x >> 6] = sabs;
    __syncthreads();
    if (threadIdx.x == 0)
        atomicAdd(&wsf[F_WABS], sh[0] + sh[1] + sh[2] + sh[3]);
}

// ---------------------------------------------------------------------------
// Pack activations: sign(x) as int8 (+1/-1), zero-padded borders and margins.
// One thread per padded pixel (incl. margins): writes 256 bytes.
__global__ void pack_x_kernel(const float* __restrict__ x,
                              int8_t* __restrict__ xi8) {
    int i = blockIdx.x * 256 + threadIdx.x;   // 421*256 = 107776 = NPP + 2*MARG
    long pp = (long)i - MARG;
    int8_t* dst = xi8 + (size_t)i * 256;

    bool interior = false;
    int b = 0, p = 0;
    if (pp >= 0 && pp < NPP) {
        b = (int)(pp / PPB);
        int r = (int)(pp - (long)b * PPB);
        int row = r / PR;
        int col = r - row * PR;
        if (row >= 1 && row <= 56 && col >= 1 && col <= 56) {
            interior = true;
            p = (row - 1) * Wn + (col - 1);
        }
    }

    if (interior) {
        const float* xp = x + (size_t)b * Cn * HWn + p;
        #pragma unroll
        for (int q = 0; q < 16; q++) {       // 16 chunks of 16 channels
            uint32_t wrd[4];
            #pragma unroll
            for (int k = 0; k < 4; k++) {
                uint32_t acc = 0;
                #pragma unroll
                for (int j = 0; j < 4; j++) {
                    float v = xp[(size_t)(q * 16 + k * 4 + j) * HWn];
                    uint32_t byte = (v < 0.0f) ? 0xFFu : 0x01u;
                    acc |= byte << (8 * j);
                }
                wrd[k] = acc;
            }
            *(uint4*)(dst + q * 16) = make_uint4(wrd[0], wrd[1], wrd[2], wrd[3]);
        }
    } else {
        uint4 z = make_uint4(0, 0, 0, 0);
        #pragma unroll
        for (int q = 0; q < 16; q++) *(uint4*)(dst + q * 16) = z;
    }
}

// ---------------------------------------------------------------------------
// MFMA i8 implicit-GEMM conv + fused shortcut + per-channel stats.
// Grid: (841, 2). Block: 256 threads = 4 waves, tile M=128 pixels x N=128 co.
__global__ __launch_bounds__(256) void conv_kernel(
    const int8_t* __restrict__ xi8p,   // points at pp_global == 0
    const int8_t* __restrict__ bpk,
    const float* __restrict__ x, float* __restrict__ wsf,
    float* __restrict__ out) {
    const int tid = threadIdx.x;
    const int w = tid >> 6, l = tid & 63;
    const int wrow = w & 1, wcol = w >> 1;

    __shared__ int   lds[64 * 129];     // 33024 B transpose buffer
    __shared__ float ssum[128], ssq[128];
    if (tid < 128) { ssum[tid] = 0.0f; ssq[tid] = 0.0f; }

    const long pp0 = (long)blockIdx.x * 128 + wrow * 64;
    // A lane base: A[m=lane&31][k=16*(lane>>5)+j], m-subtile stride 32 rows
    const int8_t* Abase0 = xi8p + (pp0 + (l & 31)) * 256 + (l >> 5) * 16;
    // B lane base: coblk0 = blockIdx.y*4 + wcol*2
    const int8_t* Bbase = bpk + ((size_t)(blockIdx.y * 4 + wcol * 2) * 64 + l) * 16;

    v16i acc[2][2] = {};

    for (int tap = 0; tap < 9; tap++) {
        int toff = (tap / 3) * 58 + (tap % 3) - 59;   // (dh-1)*58 + (dw-1)
        const int8_t* At0 = Abase0 + (long)toff * 256;
        const int8_t* At1 = At0 + 32 * 256;
        const int8_t* Bt  = Bbase + (size_t)tap * 65536;
        #pragma unroll
        for (int cib = 0; cib < 8; cib++) {
            v4i a0 = *(const v4i*)(At0 + cib * 32);
            v4i a1 = *(const v4i*)(At1 + cib * 32);
            v4i b0 = *(const v4i*)(Bt + cib * 8192);
            v4i b1 = *(const v4i*)(Bt + cib * 8192 + 1024);
            acc[0][0] = __builtin_amdgcn_mfma_i32_32x32x32_i8(a0, b0, acc[0][0], 0, 0, 0);
            acc[0][1] = __builtin_amdgcn_mfma_i32_32x32x32_i8(a0, b1, acc[0][1], 0, 0, 0);
            acc[1][0] = __builtin_amdgcn_mfma_i32_32x32x32_i8(a1, b0, acc[1][0], 0, 0, 0);
            acc[1][1] = __builtin_amdgcn_mfma_i32_32x32x32_i8(a1, b1, acc[1][1], 0, 0, 0);
        }
    }

    const float mv = wsf[F_WABS] * (1.0f / (float)WELEMS);

    // Per-lane decode for the two phases (block rows l and 64+l)
    bool   val[2];
    size_t pix[2];
    #pragma unroll
    for (int ph = 0; ph < 2; ph++) {
        long pp = (long)blockIdx.x * 128 + ph * 64 + l;
        int b = (int)(pp / PPB);
        int r = (int)(pp - (long)b * PPB);
        int row = r / PR;
        int col = r - row * PR;
        val[ph] = (row >= 1 && row <= 56 && col >= 1 && col <= 56);
        int p = (row - 1) * Wn + (col - 1);
        pix[ph] = (size_t)b * (Cn * HWn) + p;
    }

    #pragma unroll
    for (int ph = 0; ph < 2; ph++) {
        __syncthreads();
        if (wrow == ph) {
            #pragma unroll
            for (int s = 0; s < 2; s++)
                #pragma unroll
                for (int t = 0; t < 2; t++)
                    #pragma unroll
                    for (int r = 0; r < 16; r++) {
                        int mrow = s * 32 + 4 * (l >> 5) + 8 * (r >> 2) + (r & 3);
                        int ncol = wcol * 64 + t * 32 + (l & 31);
                        lds[mrow * 129 + ncol] = acc[s][t][r];
                    }
        }
        __syncthreads();
        for (int i = 0; i < 32; i++) {
            int colco = i * 4 + w;                     // wave-uniform
            int co = blockIdx.y * 128 + colco;
            float pre = 0.0f;
            if (val[ph]) {
                int dot = lds[l * 129 + colco];
                size_t idx = pix[ph] + (size_t)co * HWn;
                pre = fmaf(mv, (float)dot, x[idx]);
                out[idx] = pre;
            }
            float s1 = pre, s2 = pre * pre;
            #pragma unroll
            for (int off = 32; off; off >>= 1) {
                s1 += __shfl_down(s1, off);
                s2 += __shfl_down(s2, off);
            }
            if (l == 0) {
                atomicAdd(&ssum[colco], s1);
                atomicAdd(&ssq[colco], s2);
            }
        }
    }
    __syncthreads();
    if (tid < 128) {
        int co = blockIdx.y * 128 + tid;
        atomicAdd(&wsf[F_SUM + co], ssum[tid]);
        atomicAdd(&wsf[F_SQ  + co], ssq[tid]);
    }
}

// ---------------------------------------------------------------------------
// BN finalize + normalize + ReLU, in place on d_out. One block per (b,c) plane.
__global__ void bnrelu_kernel(float* __restrict__ out,
                              const float* __restrict__ wsf,
                              const float* __restrict__ g,
                              const float* __restrict__ bt) {
    int plane = blockIdx.x;   // b*256 + c
    int c = plane & 255;
    const float n = (float)(Bn * HWn);
    float mean = wsf[F_SUM + c] / n;
    float var  = wsf[F_SQ + c] / n - mean * mean;
    float sc = g[c] * rsqrtf(var + EPSv);
    float sh = bt[c] - mean * sc;
    float4* o4 = (float4*)(out + (size_t)plane * HWn);
    for (int i = threadIdx.x; i < HWn / 4; i += 256) {
        float4 v = o4[i];
        v.x = fmaxf(fmaf(v.x, sc, sh), 0.0f);
        v.y = fmaxf(fmaf(v.y, sc, sh), 0.0f);
        v.z = fmaxf(fmaf(v.z, sc, sh), 0.0f);
        v.w = fmaxf(fmaf(v.w, sc, sh), 0.0f);
        o4[i] = v;
    }
}

// ---------------------------------------------------------------------------
extern "C" void kernel_launch(void* const* d_in, const int* in_sizes, int n_in,
                              void* d_out, int out_size, void* d_ws, size_t ws_size,
                              hipStream_t stream) {
    const float* x     = (const float*)d_in[0];
    const float* w     = (const float*)d_in[1];
    const float* gamma = (const float*)d_in[2];
    const float* beta  = (const float*)d_in[3];
    float* out = (float*)d_out;

    float*  wsf = (float*)d_ws;
    int8_t* bpk = (int8_t*)d_ws + BPK_OFF;
    int8_t* xi8 = (int8_t*)d_ws + XI8_OFF;           // allocation start
    const int8_t* xi8p = xi8 + (size_t)MARG * 256;   // pp_global == 0

    hipMemsetAsync(d_ws, 0, STATS_BYTES, stream);
    pack_w_kernel<<<dim3(144), dim3(256), 0, stream>>>(w, wsf, bpk);
    pack_x_kernel<<<dim3(421), dim3(256), 0, stream>>>(x, xi8);
    conv_kernel<<<dim3(841, 2), dim3(256), 0, stream>>>(xi8p, bpk, x, wsf, out);
    bnrelu_kernel<<<dim3(Bn * Cn), dim3(256), 0, stream>>>(out, wsf, gamma, beta);
}

// Round 4
// 434.423 us; speedup vs baseline: 1.2019x; 1.2019x over previous
//
#include <hip/hip_runtime.h>
#include <cstdint>
#include <cstddef>

// Problem constants
#define Bn   32
#define Cn   256
#define Hn   56
#define Wn   56
#define HWn  (Hn*Wn)            // 3136
#define CHWn (Cn*HWn)
#define WELEMS (Cn*Cn*9)        // 589824
#define EPSv 1e-5f

// Padded int8 activation layout: [b][58][58][256] int8
#define PR   58
#define PPB  (PR*PR)            // 3364 padded pixels per batch
#define NPP  (Bn*PPB)           // 107648 = 841 * 128 exactly
#define MARG 64                 // guard pixels each side (tap offsets reach +/-59)

// ws layout (byte offsets)
#define F_WABS 0                // float
#define F_SUM  64               // float[256]
#define F_SQ   320              // float[256]
#define STATS_BYTES 4096
#define BPK_OFF 8192            // int8 Bpk[9][8][8][64][16] = 589824 B
#define XI8_OFF 598016          // int8 xi8[(NPP+2*MARG)*256] = 27590656 B

typedef int v4i  __attribute__((ext_vector_type(4)));
typedef int v16i __attribute__((ext_vector_type(16)));

// async global->LDS 16B copy: per-lane global addr, wave-uniform LDS base
__device__ __forceinline__ void gl_lds16(const void* g, void* l) {
    __builtin_amdgcn_global_load_lds(
        (const __attribute__((address_space(1))) unsigned int*)g,
        (__attribute__((address_space(3))) unsigned int*)l, 16, 0, 0);
}

// ---------------------------------------------------------------------------
// Pack weights into MFMA B-fragment order + reduce sum(|clip(w,-1,1)|).
// Bpk index: (((tap*8 + cib)*8 + cob)*64 + lane)*16 + j
//   byte = sign(w[co][ci][tap]), co = cob*32 + (lane&31),
//   ci = cib*32 + (lane>>5)*16 + j   (B[k][n]: n=lane&31, k=16*(lane>>5)+j)
__global__ void pack_w_kernel(const float* __restrict__ w,
                              float* __restrict__ wsf,
                              int8_t* __restrict__ bpk) {
    int u = blockIdx.x * 256 + threadIdx.x;   // 144*256 = 36864 exactly
    int lane = u & 63;
    int cob  = (u >> 6) & 7;
    int cib  = (u >> 9) & 7;
    int tap  = u >> 12;                       // 0..8
    int co  = cob * 32 + (lane & 31);
    int ci0 = cib * 32 + (lane >> 5) * 16;

    float sabs = 0.0f;
    uint32_t wrd[4];
    #pragma unroll
    for (int q = 0; q < 4; q++) {
        uint32_t acc = 0;
        #pragma unroll
        for (int j = 0; j < 4; j++) {
            float wv = w[((size_t)co * 256 + ci0 + q * 4 + j) * 9 + tap];
            sabs += fminf(fabsf(wv), 1.0f);
            uint32_t byte = (wv < 0.0f) ? 0xFFu : 0x01u;
            acc |= byte << (8 * j);
        }
        wrd[q] = acc;
    }
    *(uint4*)(bpk + (size_t)u * 16) = make_uint4(wrd[0], wrd[1], wrd[2], wrd[3]);

    #pragma unroll
    for (int off = 32; off; off >>= 1) sabs += __shfl_down(sabs, off);
    __shared__ float sh[4];
    if ((threadIdx.x & 63) == 0) sh[threadIdx.x >> 6] = sabs;
    __syncthreads();
    if (threadIdx.x == 0)
        atomicAdd(&wsf[F_WABS], sh[0] + sh[1] + sh[2] + sh[3]);
}

// ---------------------------------------------------------------------------
// Pack activations: sign(x) as int8 (+1/-1), zero-padded borders and margins.
__global__ void pack_x_kernel(const float* __restrict__ x,
                              int8_t* __restrict__ xi8) {
    int i = blockIdx.x * 256 + threadIdx.x;   // 421*256 = 107776 = NPP + 2*MARG
    long pp = (long)i - MARG;
    int8_t* dst = xi8 + (size_t)i * 256;

    bool interior = false;
    int b = 0, p = 0;
    if (pp >= 0 && pp < NPP) {
        b = (int)(pp / PPB);
        int r = (int)(pp - (long)b * PPB);
        int row = r / PR;
        int col = r - row * PR;
        if (row >= 1 && row <= 56 && col >= 1 && col <= 56) {
            interior = true;
            p = (row - 1) * Wn + (col - 1);
        }
    }

    if (interior) {
        const float* xp = x + (size_t)b * CHWn + p;
        #pragma unroll
        for (int q = 0; q < 16; q++) {       // 16 chunks of 16 channels
            uint32_t wrd[4];
            #pragma unroll
            for (int k = 0; k < 4; k++) {
                uint32_t acc = 0;
                #pragma unroll
                for (int j = 0; j < 4; j++) {
                    float v = xp[(size_t)(q * 16 + k * 4 + j) * HWn];
                    uint32_t byte = (v < 0.0f) ? 0xFFu : 0x01u;
                    acc |= byte << (8 * j);
                }
                wrd[k] = acc;
            }
            *(uint4*)(dst + q * 16) = make_uint4(wrd[0], wrd[1], wrd[2], wrd[3]);
        }
    } else {
        uint4 z = make_uint4(0, 0, 0, 0);
        #pragma unroll
        for (int q = 0; q < 16; q++) *(uint4*)(dst + q * 16) = z;
    }
}

// ---------------------------------------------------------------------------
// MFMA i8 implicit-GEMM conv, m97-style: A staged via global_load_lds with
// LDS double-buffer; B direct from global (L2-hot, fragment-ordered).
// Grid (841, 2). Block 256 = 4 waves; wave tile 64px x 64co; block 128x128.
__global__ __launch_bounds__(256, 3) void conv_kernel(
    const int8_t* __restrict__ xi8p,   // points at pp_global == 0
    const int8_t* __restrict__ bpk,
    const float* __restrict__ x, float* __restrict__ wsf,
    float* __restrict__ out) {
    const int tid = threadIdx.x;
    const int w = tid >> 6, l = tid & 63;
    const int wm = w & 1, wn = w >> 1;

    // union: K-loop A double-buffer (2x4KB) / epilogue cf[64][129] floats
    __shared__ __align__(16) char smem[64 * 129 * 4];   // 33024 B

    const long pp0 = (long)blockIdx.x * 128;

    // A-stage per-thread global base: tid -> g=tid>>6, h=(tid>>5)&1, px=tid&31
    //   pixel = pp0 + toff + g*32 + px ; byte = cib*32 + h*16
    // LDS slot = tid*16  (== g*1024 + h*512 + px*16)
    const int8_t* AgBase = xi8p + (pp0 + (long)(tid >> 6) * 32 + (tid & 31)) * 256
                               + ((tid >> 5) & 1) * 16;
    char* AldsW = smem + w * 1024;     // wave-uniform base (+ buf*4096)

    // B per-lane fragment base: cob0 = blockIdx.y*4 + wn*2
    const int8_t* Bg = bpk + ((size_t)((blockIdx.y * 4 + wn * 2) * 64 + l)) * 16;

    v16i acc[2][2] = {};

    // prologue: stage slice (tap=0 -> toff=-59, cib=0) into buf 0
    gl_lds16(AgBase + (long)(-59) * 256, AldsW);

    for (int tap = 0; tap < 9; tap++) {
        int dh = (tap * 11) >> 5;               // tap/3 for 0..8
        int toff = dh * PR + (tap - dh * 3) - 59;
        int tap1 = tap + 1;
        int dh1 = (tap1 * 11) >> 5;
        int toff1 = dh1 * PR + (tap1 - dh1 * 3) - 59;
        const int8_t* Bt = Bg + (size_t)tap * 65536;
        #pragma unroll
        for (int cib = 0; cib < 8; cib++) {
            const int buf = cib & 1;
            __syncthreads();   // drains staged loads for this slice; protects buf^1
            // prefetch next slice's A into buf^1
            if (cib < 7) {
                gl_lds16(AgBase + (long)toff * 256 + (cib + 1) * 32,
                         smem + (buf ^ 1) * 4096 + w * 1024);
            } else if (tap < 8) {
                gl_lds16(AgBase + (long)toff1 * 256,
                         smem + (buf ^ 1) * 4096 + w * 1024);
            }
            // B fragments direct from global (coalesced, L2-hot)
            v4i b0 = *(const v4i*)(Bt + cib * 8192);
            v4i b1 = *(const v4i*)(Bt + cib * 8192 + 1024);
            // A fragments from LDS
            const char* Ab = smem + buf * 4096;
            v4i a0 = *(const v4i*)(Ab + (wm * 2 + 0) * 1024 + (l >> 5) * 512 + (l & 31) * 16);
            v4i a1 = *(const v4i*)(Ab + (wm * 2 + 1) * 1024 + (l >> 5) * 512 + (l & 31) * 16);
            acc[0][0] = __builtin_amdgcn_mfma_i32_32x32x32_i8(a0, b0, acc[0][0], 0, 0, 0);
            acc[0][1] = __builtin_amdgcn_mfma_i32_32x32x32_i8(a0, b1, acc[0][1], 0, 0, 0);
            acc[1][0] = __builtin_amdgcn_mfma_i32_32x32x32_i8(a1, b0, acc[1][0], 0, 0, 0);
            acc[1][1] = __builtin_amdgcn_mfma_i32_32x32x32_i8(a1, b1, acc[1][1], 0, 0, 0);
        }
    }

    // ----- fused epilogue: shortcut + store + per-channel stats -----
    const float mv = wsf[F_WABS] * (1.0f / (float)WELEMS);

    bool val[2]; size_t pix[2];
    #pragma unroll
    for (int ph = 0; ph < 2; ph++) {
        long pp = pp0 + ph * 64 + l;
        int b = (int)(pp / PPB);
        int r = (int)(pp - (long)b * PPB);
        int row = r / PR;
        int col = r - row * PR;
        val[ph] = (row >= 1 && row <= 56 && col >= 1 && col <= 56);
        pix[ph] = (size_t)b * CHWn + (size_t)((row - 1) * Wn + (col - 1));
    }

    float* cf = (float*)smem;
    float s1 = 0.0f, s2 = 0.0f;
    const int co_l = tid & 127;
    const int px0 = (tid >> 7) * 32;

    for (int ph = 0; ph < 2; ph++) {
        __syncthreads();
        if (wm == ph) {   // 2 writer waves cover 64px x 128co
            #pragma unroll
            for (int s = 0; s < 2; s++)
                #pragma unroll
                for (int t = 0; t < 2; t++)
                    #pragma unroll
                    for (int r = 0; r < 16; r++) {
                        int mrow = s * 32 + 4 * (l >> 5) + 8 * (r >> 2) + (r & 3);
                        int ncol = wn * 64 + t * 32 + (l & 31);
                        cf[mrow * 129 + ncol] = (float)acc[s][t][r];
                    }
        }
        __syncthreads();
        // (a) shortcut + store; write pre back for stats (lane = pixel)
        #pragma unroll 4
        for (int j = 0; j < 32; j++) {
            int co = w + 4 * j;
            float dot = cf[l * 129 + co];
            float pre = 0.0f;
            if (val[ph]) {
                size_t idx = pix[ph] + (size_t)(blockIdx.y * 128 + co) * HWn;
                pre = fmaf(mv, dot, x[idx]);
                out[idx] = pre;
            }
            cf[l * 129 + co] = pre;
        }
        __syncthreads();
        // (b) stats: fixed co per thread, register accumulation, no shuffles
        #pragma unroll 8
        for (int i = 0; i < 32; i++) {
            float v = cf[(px0 + i) * 129 + co_l];
            s1 += v; s2 += v * v;
        }
    }
    atomicAdd(&wsf[F_SUM + blockIdx.y * 128 + co_l], s1);
    atomicAdd(&wsf[F_SQ  + blockIdx.y * 128 + co_l], s2);
}

// ---------------------------------------------------------------------------
// BN finalize + normalize + ReLU, in place on d_out. One block per (b,c) plane.
__global__ void bnrelu_kernel(float* __restrict__ out,
                              const float* __restrict__ wsf,
                              const float* __restrict__ g,
                              const float* __restrict__ bt) {
    int plane = blockIdx.x;   // b*256 + c
    int c = plane & 255;
    const float n = (float)(Bn * HWn);
    float mean = wsf[F_SUM + c] / n;
    float var  = wsf[F_SQ + c] / n - mean * mean;
    float sc = g[c] * rsqrtf(var + EPSv);
    float sh = bt[c] - mean * sc;
    float4* o4 = (float4*)(out + (size_t)plane * HWn);
    for (int i = threadIdx.x; i < HWn / 4; i += 256) {
        float4 v = o4[i];
        v.x = fmaxf(fmaf(v.x, sc, sh), 0.0f);
        v.y = fmaxf(fmaf(v.y, sc, sh), 0.0f);
        v.z = fmaxf(fmaf(v.z, sc, sh), 0.0f);
        v.w = fmaxf(fmaf(v.w, sc, sh), 0.0f);
        o4[i] = v;
    }
}

// ---------------------------------------------------------------------------
extern "C" void kernel_launch(void* const* d_in, const int* in_sizes, int n_in,
                              void* d_out, int out_size, void* d_ws, size_t ws_size,
                              hipStream_t stream) {
    const float* x     = (const float*)d_in[0];
    const float* w     = (const float*)d_in[1];
    const float* gamma = (const float*)d_in[2];
    const float* beta  = (const float*)d_in[3];
    float* out = (float*)d_out;

    float*  wsf = (float*)d_ws;
    int8_t* bpk = (int8_t*)d_ws + BPK_OFF;
    int8_t* xi8 = (int8_t*)d_ws + XI8_OFF;           // allocation start
    const int8_t* xi8p = xi8 + (size_t)MARG * 256;   // pp_global == 0

    hipMemsetAsync(d_ws, 0, STATS_BYTES, stream);
    pack_w_kernel<<<dim3(144), dim3(256), 0, stream>>>(w, wsf, bpk);
    pack_x_kernel<<<dim3(421), dim3(256), 0, stream>>>(x, xi8);
    conv_kernel<<<dim3(841, 2), dim3(256), 0, stream>>>(xi8p, bpk, x, wsf, out);
    bnrelu_kernel<<<dim3(Bn * Cn), dim3(256), 0, stream>>>(out, wsf, gamma, beta);
}

// Round 5
// 430.627 us; speedup vs baseline: 1.2125x; 1.0088x over previous
//
#include <hip/hip_runtime.h>
#include <cstdint>
#include <cstddef>

// Problem constants
#define Bn   32
#define Cn   256
#define Hn   56
#define Wn   56
#define HWn  (Hn*Wn)            // 3136
#define CHWn (Cn*HWn)
#define WELEMS (Cn*Cn*9)        // 589824
#define EPSv 1e-5f

// Padded int8 activation layout: [b][58][58][256] int8
#define PR   58
#define PPB  (PR*PR)            // 3364 padded pixels per batch
#define NPP  (Bn*PPB)           // 107648 = 841 * 128 exactly
#define MARG 64                 // guard pixels each side (tap offsets reach +/-59)

// Staged A region per block: pixels [pp0-59, pp0+128+59) = 246 px
#define STAGE_PX 246
#define STAGE_BYTES (STAGE_PX*256)   // 62976

// ws layout (byte offsets)
#define F_WABS 0                // float
#define F_SUM  64               // float[256]
#define F_SQ   320              // float[256]
#define STATS_BYTES 4096
#define BPK_OFF 8192            // int8 Bpk[9][8][8][64][16] = 589824 B
#define XI8_OFF 598016          // int8 xi8[(NPP+2*MARG)*256] = 27590656 B

typedef int v4i  __attribute__((ext_vector_type(4)));
typedef int v16i __attribute__((ext_vector_type(16)));

// async global->LDS 16B copy: per-lane global addr, wave-uniform LDS base
__device__ __forceinline__ void gl_lds16(const void* g, void* l) {
    __builtin_amdgcn_global_load_lds(
        (const __attribute__((address_space(1))) unsigned int*)g,
        (__attribute__((address_space(3))) unsigned int*)l, 16, 0, 0);
}

// ---------------------------------------------------------------------------
// Pack weights into MFMA B-fragment order + reduce sum(|clip(w,-1,1)|).
// Bpk index: (((tap*8 + cib)*8 + cob)*64 + lane)*16 + j
//   byte = sign(w[co][ci][tap]), co = cob*32 + (lane&31),
//   ci = cib*32 + (lane>>5)*16 + j   (B[k][n]: n=lane&31, k=16*(lane>>5)+j)
__global__ void pack_w_kernel(const float* __restrict__ w,
                              float* __restrict__ wsf,
                              int8_t* __restrict__ bpk) {
    int u = blockIdx.x * 256 + threadIdx.x;   // 144*256 = 36864 exactly
    int lane = u & 63;
    int cob  = (u >> 6) & 7;
    int cib  = (u >> 9) & 7;
    int tap  = u >> 12;                       // 0..8
    int co  = cob * 32 + (lane & 31);
    int ci0 = cib * 32 + (lane >> 5) * 16;

    float sabs = 0.0f;
    uint32_t wrd[4];
    #pragma unroll
    for (int q = 0; q < 4; q++) {
        uint32_t acc = 0;
        #pragma unroll
        for (int j = 0; j < 4; j++) {
            float wv = w[((size_t)co * 256 + ci0 + q * 4 + j) * 9 + tap];
            sabs += fminf(fabsf(wv), 1.0f);
            uint32_t byte = (wv < 0.0f) ? 0xFFu : 0x01u;
            acc |= byte << (8 * j);
        }
        wrd[q] = acc;
    }
    *(uint4*)(bpk + (size_t)u * 16) = make_uint4(wrd[0], wrd[1], wrd[2], wrd[3]);

    #pragma unroll
    for (int off = 32; off; off >>= 1) sabs += __shfl_down(sabs, off);
    __shared__ float sh[4];
    if ((threadIdx.x & 63) == 0) sh[threadIdx.x >> 6] = sabs;
    __syncthreads();
    if (threadIdx.x == 0)
        atomicAdd(&wsf[F_WABS], sh[0] + sh[1] + sh[2] + sh[3]);
}

// ---------------------------------------------------------------------------
// Pack activations: sign(x) as int8 (+1/-1), zero-padded borders and margins.
__global__ void pack_x_kernel(const float* __restrict__ x,
                              int8_t* __restrict__ xi8) {
    int i = blockIdx.x * 256 + threadIdx.x;   // 421*256 = 107776 = NPP + 2*MARG
    long pp = (long)i - MARG;
    int8_t* dst = xi8 + (size_t)i * 256;

    bool interior = false;
    int b = 0, p = 0;
    if (pp >= 0 && pp < NPP) {
        b = (int)(pp / PPB);
        int r = (int)(pp - (long)b * PPB);
        int row = r / PR;
        int col = r - row * PR;
        if (row >= 1 && row <= 56 && col >= 1 && col <= 56) {
            interior = true;
            p = (row - 1) * Wn + (col - 1);
        }
    }

    if (interior) {
        const float* xp = x + (size_t)b * CHWn + p;
        #pragma unroll
        for (int q = 0; q < 16; q++) {       // 16 chunks of 16 channels
            uint32_t wrd[4];
            #pragma unroll
            for (int k = 0; k < 4; k++) {
                uint32_t acc = 0;
                #pragma unroll
                for (int j = 0; j < 4; j++) {
                    float v = xp[(size_t)(q * 16 + k * 4 + j) * HWn];
                    uint32_t byte = (v < 0.0f) ? 0xFFu : 0x01u;
                    acc |= byte << (8 * j);
                }
                wrd[k] = acc;
            }
            *(uint4*)(dst + q * 16) = make_uint4(wrd[0], wrd[1], wrd[2], wrd[3]);
        }
    } else {
        uint4 z = make_uint4(0, 0, 0, 0);
        #pragma unroll
        for (int q = 0; q < 16; q++) *(uint4*)(dst + q * 16) = z;
    }
}

// ---------------------------------------------------------------------------
// MFMA i8 implicit-GEMM conv: A staged ONCE into LDS (XOR-16 swizzled),
// then a barrier-free 72-slice K-loop; B direct from global (L2-hot).
// Grid (841). Block 256 = 4 waves. Tile M=128 px x N=256 co.
// Wave (wm=w&1, wn=w>>1): 64 px x 128 co -> acc[2][4] v16i.
__global__ __launch_bounds__(256, 2) void conv_kernel(
    const int8_t* __restrict__ xi8p,   // points at pp_global == 0
    const int8_t* __restrict__ bpk,
    const float* __restrict__ x, float* __restrict__ wsf,
    float* __restrict__ out) {
    const int tid = threadIdx.x;
    const int w = tid >> 6, l = tid & 63;
    const int wm = w & 1, wn = w >> 1;

    __shared__ __align__(16) char smem[STAGE_BYTES];   // 62976 B (union: cf)

    const long pp0 = (long)blockIdx.x * 128;
    const long gp0 = pp0 - 59;

    // ---- stage A once: LDS 16B-slot m (pixel p=m>>4, slot c=m&15) holds
    //      G[p][c ^ (p&15)]  (XOR swizzle applied on the global source) ----
    {
        const int c0 = tid & 15;
        #pragma unroll
        for (int i = 0; i < 16; i++) {
            int slot = i * 4096 + tid * 16;
            if (slot < STAGE_BYTES) {
                int p = slot >> 8;                 // i*16 + (tid>>4)
                int c = c0 ^ (p & 15);
                gl_lds16(xi8p + (gp0 + p) * 256 + c * 16,
                         smem + i * 4096 + w * 1024);
            }
        }
    }
    __syncthreads();   // compiler emits vmcnt(0) drain here — the ONLY K barrier

    v16i acc[2][4] = {};
    const int plane0 = wm * 64 + (l & 31);     // pixel base within tile (+tbase,+s*32)
    const int h = (l >> 5) & 1;

    for (int tap = 0; tap < 9; tap++) {
        int dh = tap / 3;
        int tbase = dh * PR + (tap - 3 * dh);  // toff + 59, in {0..2,58..60,116..118}
        int pA = tbase + plane0;
        const int8_t* Btap = bpk + ((size_t)tap * 8 * 8 + wn * 4) * 1024 + l * 16;
        #pragma unroll
        for (int cib = 0; cib < 8; cib++) {
            int cw = cib * 2 + h;
            int p0 = pA, p1 = pA + 32;
            v4i a0 = *(const v4i*)(smem + p0 * 256 + ((cw ^ (p0 & 15)) << 4));
            v4i a1 = *(const v4i*)(smem + p1 * 256 + ((cw ^ (p1 & 15)) << 4));
            const int8_t* Bc = Btap + (size_t)cib * 8192;
            v4i b0 = *(const v4i*)(Bc);
            v4i b1 = *(const v4i*)(Bc + 1024);
            v4i b2 = *(const v4i*)(Bc + 2048);
            v4i b3 = *(const v4i*)(Bc + 3072);
            acc[0][0] = __builtin_amdgcn_mfma_i32_32x32x32_i8(a0, b0, acc[0][0], 0, 0, 0);
            acc[1][0] = __builtin_amdgcn_mfma_i32_32x32x32_i8(a1, b0, acc[1][0], 0, 0, 0);
            acc[0][1] = __builtin_amdgcn_mfma_i32_32x32x32_i8(a0, b1, acc[0][1], 0, 0, 0);
            acc[1][1] = __builtin_amdgcn_mfma_i32_32x32x32_i8(a1, b1, acc[1][1], 0, 0, 0);
            acc[0][2] = __builtin_amdgcn_mfma_i32_32x32x32_i8(a0, b2, acc[0][2], 0, 0, 0);
            acc[1][2] = __builtin_amdgcn_mfma_i32_32x32x32_i8(a1, b2, acc[1][2], 0, 0, 0);
            acc[0][3] = __builtin_amdgcn_mfma_i32_32x32x32_i8(a0, b3, acc[0][3], 0, 0, 0);
            acc[1][3] = __builtin_amdgcn_mfma_i32_32x32x32_i8(a1, b3, acc[1][3], 0, 0, 0);
        }
    }

    // ----- fused epilogue: shortcut + store + per-channel stats -----
    const float mv = wsf[F_WABS] * (1.0f / (float)WELEMS);

    bool val[2]; size_t pix[2];
    #pragma unroll
    for (int ph = 0; ph < 2; ph++) {
        long pp = pp0 + ph * 64 + l;
        int b = (int)(pp / PPB);
        int r = (int)(pp - (long)b * PPB);
        int row = r / PR;
        int col = r - row * PR;
        val[ph] = (row >= 1 && row <= 56 && col >= 1 && col <= 56);
        pix[ph] = (size_t)b * CHWn + (size_t)((row - 1) * Wn + (col - 1));
    }

    float* cf = (float*)smem;                  // 64 x 129 floats = 33024 B
    float s1[2] = {0.0f, 0.0f}, s2[2] = {0.0f, 0.0f};
    const int co_l = tid & 127;
    const int px0 = (tid >> 7) * 32;

    for (int ph = 0; ph < 2; ph++) {
        #pragma unroll
        for (int cu = 0; cu < 2; cu++) {
            __syncthreads();
            if (wm == ph && wn == cu) {        // single writer wave
                #pragma unroll
                for (int s = 0; s < 2; s++)
                    #pragma unroll
                    for (int t = 0; t < 4; t++)
                        #pragma unroll
                        for (int r = 0; r < 16; r++) {
                            int mrow = s * 32 + 4 * (l >> 5) + 8 * (r >> 2) + (r & 3);
                            int ncol = t * 32 + (l & 31);
                            cf[mrow * 129 + ncol] = (float)acc[s][t][r];
                        }
            }
            __syncthreads();
            // (a) shortcut + store (lane = pixel); write pre back for stats
            #pragma unroll 4
            for (int j = 0; j < 32; j++) {
                int co = w + 4 * j;            // 0..127 within this half
                float dot = cf[l * 129 + co];
                float pre = 0.0f;
                if (val[ph]) {
                    size_t idx = pix[ph] + (size_t)(cu * 128 + co) * HWn;
                    pre = fmaf(mv, dot, x[idx]);
                    out[idx] = pre;
                }
                cf[l * 129 + co] = pre;
            }
            __syncthreads();
            // (b) stats: fixed co per thread, register accumulation
            #pragma unroll 8
            for (int i = 0; i < 32; i++) {
                float v = cf[(px0 + i) * 129 + co_l];
                s1[cu] += v; s2[cu] += v * v;
            }
        }
    }
    #pragma unroll
    for (int cu = 0; cu < 2; cu++) {
        atomicAdd(&wsf[F_SUM + cu * 128 + co_l], s1[cu]);
        atomicAdd(&wsf[F_SQ  + cu * 128 + co_l], s2[cu]);
    }
}

// ---------------------------------------------------------------------------
// BN finalize + normalize + ReLU, in place on d_out. One block per (b,c) plane.
__global__ void bnrelu_kernel(float* __restrict__ out,
                              const float* __restrict__ wsf,
                              const float* __restrict__ g,
                              const float* __restrict__ bt) {
    int plane = blockIdx.x;   // b*256 + c
    int c = plane & 255;
    const float n = (float)(Bn * HWn);
    float mean = wsf[F_SUM + c] / n;
    float var  = wsf[F_SQ + c] / n - mean * mean;
    float sc = g[c] * rsqrtf(var + EPSv);
    float sh = bt[c] - mean * sc;
    float4* o4 = (float4*)(out + (size_t)plane * HWn);
    for (int i = threadIdx.x; i < HWn / 4; i += 256) {
        float4 v = o4[i];
        v.x = fmaxf(fmaf(v.x, sc, sh), 0.0f);
        v.y = fmaxf(fmaf(v.y, sc, sh), 0.0f);
        v.z = fmaxf(fmaf(v.z, sc, sh), 0.0f);
        v.w = fmaxf(fmaf(v.w, sc, sh), 0.0f);
        o4[i] = v;
    }
}

// ---------------------------------------------------------------------------
extern "C" void kernel_launch(void* const* d_in, const int* in_sizes, int n_in,
                              void* d_out, int out_size, void* d_ws, size_t ws_size,
                              hipStream_t stream) {
    const float* x     = (const float*)d_in[0];
    const float* w     = (const float*)d_in[1];
    const float* gamma = (const float*)d_in[2];
    const float* beta  = (const float*)d_in[3];
    float* out = (float*)d_out;

    float*  wsf = (float*)d_ws;
    int8_t* bpk = (int8_t*)d_ws + BPK_OFF;
    int8_t* xi8 = (int8_t*)d_ws + XI8_OFF;           // allocation start
    const int8_t* xi8p = xi8 + (size_t)MARG * 256;   // pp_global == 0

    hipMemsetAsync(d_ws, 0, STATS_BYTES, stream);
    pack_w_kernel<<<dim3(144), dim3(256), 0, stream>>>(w, wsf, bpk);
    pack_x_kernel<<<dim3(421), dim3(256), 0, stream>>>(x, xi8);
    conv_kernel<<<dim3(841), dim3(256), 0, stream>>>(xi8p, bpk, x, wsf, out);
    bnrelu_kernel<<<dim3(Bn * Cn), dim3(256), 0, stream>>>(out, wsf, gamma, beta);
}